// Round 1
// baseline (784.218 us; speedup 1.0000x reference)
//
#include <hip/hip_runtime.h>
#include <stdint.h>

#define EMB 768
#define NBATCH 8
#define SEQ 2048
#define M_TOT (NBATCH*SEQ)   // 16384

using bf16x8 = __attribute__((ext_vector_type(8))) short;
using f32x4  = __attribute__((ext_vector_type(4))) float;

__device__ __forceinline__ short f2bf(float f) {
  __bf16 h = (__bf16)f;                // RNE convert, compiler emits v_cvt_pk when vectorized
  return __builtin_bit_cast(short, h);
}
__device__ __forceinline__ unsigned packbf(float a, float b) {
  return (unsigned)(unsigned short)f2bf(a) | ((unsigned)(unsigned short)f2bf(b) << 16);
}
__device__ __forceinline__ f32x4 MFMA(bf16x8 a, bf16x8 b, f32x4 c) {
  return __builtin_amdgcn_mfma_f32_16x16x32_bf16(a, b, c, 0, 0, 0);
}
#define GLOAD_LDS16(g, l) __builtin_amdgcn_global_load_lds( \
    (const __attribute__((address_space(1))) unsigned int*)(g), \
    (__attribute__((address_space(3))) unsigned int*)(l), 16, 0, 0)

// ---------------------------------------------------------------------------
// QKV projection: C[m,f] = sum_e x[m,e] * W[f,e], f in [0,2304) -> Q|K|V.
// 128x128 tile, BK=64, 256 threads (2x2 waves), reg-staged fp32->bf16 convert,
// XOR-swizzled LDS (chunk ^= row&7), double-buffered.
// V (f>=1536) is written TRANSPOSED: Vt[b][f][s].
// ---------------------------------------------------------------------------
__global__ __launch_bounds__(256, 2) void qkv_gemm(
    const float* __restrict__ x, const float* __restrict__ Wq,
    const float* __restrict__ Wk, const float* __restrict__ Wv,
    short* __restrict__ Qb, short* __restrict__ Kb, short* __restrict__ Vt)
{
  __shared__ short As[2][128*64];
  __shared__ short Bs[2][128*64];

  const int bid = blockIdx.x;
  const int nb = (bid & 7) * 288 + (bid >> 3);     // XCD swizzle (2304 % 8 == 0)
  const int bm = nb / 18, bn = nb % 18;
  const int mbase = bm * 128;

  const int wi = bn / 6;                           // 0:Q 1:K 2:V
  const float* Wsrc = (wi == 0) ? Wq : (wi == 1) ? Wk : Wv;
  const float* xsrc = x + (size_t)mbase * EMB;
  const float* wsrc = Wsrc + (size_t)(bn % 6) * 128 * EMB;

  const int t = threadIdx.x;
  const int lane = t & 63, w = t >> 6;
  const int wm = w >> 1, wn = w & 1;
  const int l15 = lane & 15, l4 = lane >> 4;

  f32x4 acc[4][4] = {};
  float4 sa[4][2], sb[4][2];

  auto stage_load = [&](int kk) {
    const int k0 = kk * 64;
#pragma unroll
    for (int i = 0; i < 4; ++i) {
      int cid = i * 256 + t, row = cid >> 3, cc = cid & 7;
      const float4* pa = reinterpret_cast<const float4*>(xsrc + (size_t)row * EMB + k0 + cc * 8);
      sa[i][0] = pa[0]; sa[i][1] = pa[1];
      const float4* pb = reinterpret_cast<const float4*>(wsrc + (size_t)row * EMB + k0 + cc * 8);
      sb[i][0] = pb[0]; sb[i][1] = pb[1];
    }
  };
  auto stage_write = [&](int p) {
#pragma unroll
    for (int i = 0; i < 4; ++i) {
      int cid = i * 256 + t, row = cid >> 3, cc = cid & 7;
      int dst = row * 64 + ((cc ^ (row & 7)) << 3);
      int4 va, vb;
      va.x = (int)packbf(sa[i][0].x, sa[i][0].y); va.y = (int)packbf(sa[i][0].z, sa[i][0].w);
      va.z = (int)packbf(sa[i][1].x, sa[i][1].y); va.w = (int)packbf(sa[i][1].z, sa[i][1].w);
      *reinterpret_cast<int4*>(&As[p][dst]) = va;
      vb.x = (int)packbf(sb[i][0].x, sb[i][0].y); vb.y = (int)packbf(sb[i][0].z, sb[i][0].w);
      vb.z = (int)packbf(sb[i][1].x, sb[i][1].y); vb.w = (int)packbf(sb[i][1].z, sb[i][1].w);
      *reinterpret_cast<int4*>(&Bs[p][dst]) = vb;
    }
  };
  auto domfma = [&](int p) {
#pragma unroll
    for (int ks = 0; ks < 2; ++ks) {
      bf16x8 a[4], b[4];
#pragma unroll
      for (int i = 0; i < 4; ++i) {
        int ra = wm * 64 + i * 16 + l15;
        a[i] = *reinterpret_cast<const bf16x8*>(&As[p][ra * 64 + (((ks * 4 + l4) ^ (ra & 7)) << 3)]);
        int rb = wn * 64 + i * 16 + l15;
        b[i] = *reinterpret_cast<const bf16x8*>(&Bs[p][rb * 64 + (((ks * 4 + l4) ^ (rb & 7)) << 3)]);
      }
#pragma unroll
      for (int mi = 0; mi < 4; ++mi)
#pragma unroll
        for (int ni = 0; ni < 4; ++ni)
          acc[mi][ni] = MFMA(a[mi], b[ni], acc[mi][ni]);
    }
  };

  stage_load(0); stage_write(0);
  __syncthreads();
  for (int kk = 0; kk < 12; ++kk) {
    int p = kk & 1;
    if (kk < 11) stage_load(kk + 1);
    domfma(p);
    if (kk < 11) stage_write(p ^ 1);
    __syncthreads();
  }

#pragma unroll
  for (int mi = 0; mi < 4; ++mi) {
#pragma unroll
    for (int ni = 0; ni < 4; ++ni) {
      int f = bn * 128 + wn * 64 + ni * 16 + l15;
      int m0 = mbase + wm * 64 + mi * 16 + l4 * 4;
      f32x4 v = acc[mi][ni];
      if (f < 1536) {
        short* dst = (f < 768) ? (Qb + f) : (Kb + (f - 768));
#pragma unroll
        for (int j = 0; j < 4; ++j)
          dst[(size_t)(m0 + j) * EMB] = f2bf(v[j]);
      } else {
        int f2 = f - 1536, bb = m0 >> 11, s = m0 & 2047;
        short4 pk = make_short4(f2bf(v[0]), f2bf(v[1]), f2bf(v[2]), f2bf(v[3]));
        *reinterpret_cast<short4*>(&Vt[((size_t)bb * EMB + f2) * SEQ + s]) = pk;
      }
    }
  }
}

// ---------------------------------------------------------------------------
// Flash attention: 256 blocks = (batch, 64-row q tile), 512 threads (8 waves).
// QK^T waves: (qr = w>>1, kh = w&1); PV waves: d-slice w*96.
// K chunk [64][768] staged via global_load_lds (pre-swizzled global source,
// linear LDS dest); Q in registers; V read direct from global (Vt layout);
// P via swizzled LDS; online softmax state in LDS, exp2 units.
// ---------------------------------------------------------------------------
__global__ __launch_bounds__(512, 2) void attn(
    const short* __restrict__ Qb, const short* __restrict__ Kb,
    const short* __restrict__ Vt, const int* __restrict__ mask,
    float* __restrict__ out)
{
  extern __shared__ char smem[];
  short* Klds = (short*)smem;                      // [64][768] swizzled, 96KB
  short* Plds = (short*)(smem + 64*768*2);         // [64][64]  swizzled, 8KB
  float* m_lds    = (float*)(smem + 64*768*2 + 64*64*2);
  float* l_lds    = m_lds + 64;
  float* al_lds   = l_lds + 64;
  float* pmax_lds = al_lds + 64;                   // [64][2]
  float* psum_lds = pmax_lds + 128;                // [64][2]

  const int tid = threadIdx.x;
  const int lane = tid & 63, w = tid >> 6;
  const int l15 = lane & 15, l4 = lane >> 4;
  const int qr = w >> 1, kh = w & 1;

  const int bid = blockIdx.x;
  const int nb = (bid & 7) * 32 + (bid >> 3);      // same-batch blocks -> same XCD
  const int b = nb >> 5, qb = nb & 31;

  if (tid < 64) {
    m_lds[tid] = -3.0e38f;
    l_lds[tid] = 0.f;
    al_lds[tid] = 1.f;
    psum_lds[tid*2] = 0.f; psum_lds[tid*2+1] = 0.f;
  }

  // Q fragments in registers: 16 rows x 768, A-layout (row=l15, k=l4*8+j)
  bf16x8 q[24];
  {
    const short* qsrc = Qb + ((size_t)(b*SEQ + qb*64 + qr*16 + l15)) * EMB + l4*8;
#pragma unroll
    for (int d = 0; d < 24; ++d)
      q[d] = *reinterpret_cast<const bf16x8*>(qsrc + d*32);
  }

  f32x4 acc[4][6] = {};

  const short* kcbase = Kb + (size_t)b * SEQ * EMB;
  auto stageK = [&](int kc) {
    const short* src = kcbase + (size_t)kc * 64 * EMB;
#pragma unroll
    for (int i = 0; i < 12; ++i) {
      int slot = i*512 + tid;
      int key = slot / 96, c = slot % 96;
      int csw = c ^ (key & 7);                     // pre-swizzled global source
      GLOAD_LDS16(src + (size_t)key*EMB + csw*8,
                  (char*)Klds + (size_t)(i*512 + w*64)*16);
    }
  };

  stageK(0);
  asm volatile("s_waitcnt vmcnt(0)" ::: "memory");
  __syncthreads();

  const float SCL = 1.4426950408889634f / 27.712812921102035f;  // log2(e)/sqrt(768)
  const int* mrow = mask + (size_t)b * SEQ * SEQ;

  for (int kc = 0; kc < 32; ++kc) {
    // ---- QK^T: this wave's S[16 q][32 k] over full 768 d ----
    f32x4 s0 = {0,0,0,0}, s1 = {0,0,0,0};
#pragma unroll
    for (int d = 0; d < 24; ++d) {
      int key0 = kh*32 + l15, key1 = key0 + 16;
      int cd = d*4 + l4;
      bf16x8 b0 = *reinterpret_cast<const bf16x8*>(&Klds[key0*EMB + ((cd ^ (key0 & 7)) << 3)]);
      bf16x8 b1 = *reinterpret_cast<const bf16x8*>(&Klds[key1*EMB + ((cd ^ (key1 & 7)) << 3)]);
      s0 = MFMA(q[d], b0, s0);
      s1 = MFMA(q[d], b1, s1);
    }

    // scale + mask -> t (exp2 units)
    float t0[4], t1[4];
    const int q0 = qb*64 + qr*16 + l4*4;
    const int kg = kc*64 + kh*32 + l15;
#pragma unroll
    for (int j = 0; j < 4; ++j) {
      const int* mp = mrow + (size_t)(q0 + j) * SEQ + kg;
      t0[j] = (mp[0]  != 0) ? s0[j] * SCL : -3.0e38f;
      t1[j] = (mp[16] != 0) ? s1[j] * SCL : -3.0e38f;
    }
    // partial row max over this wave's 32 keys
    float pm[4];
#pragma unroll
    for (int j = 0; j < 4; ++j) pm[j] = fmaxf(t0[j], t1[j]);
#pragma unroll
    for (int off = 8; off >= 1; off >>= 1)
#pragma unroll
      for (int j = 0; j < 4; ++j) pm[j] = fmaxf(pm[j], __shfl_xor(pm[j], off));
    if (l15 == 0) {
#pragma unroll
      for (int j = 0; j < 4; ++j) pmax_lds[(qr*16 + l4*4 + j)*2 + kh] = pm[j];
    }
    __syncthreads();                               // barrier1: QK reads of Klds done

    if (kc + 1 < 32) stageK(kc + 1);               // prefetch next K chunk

    if (tid < 64) {                                // wave0: m/alpha/deferred-l pass
      float mo = m_lds[tid];
      l_lds[tid] = l_lds[tid] * al_lds[tid] + psum_lds[tid*2] + psum_lds[tid*2+1];
      float mn = fmaxf(mo, fmaxf(pmax_lds[tid*2], pmax_lds[tid*2+1]));
      al_lds[tid] = __builtin_amdgcn_exp2f(mo - mn);
      m_lds[tid] = mn;
    }
    __syncthreads();                               // barrier2

    // P = exp2(t - m), row partial sums, write P (bf16, swizzled LDS)
    float mr[4];
#pragma unroll
    for (int j = 0; j < 4; ++j) mr[j] = m_lds[qr*16 + l4*4 + j];
    float ps[4];
#pragma unroll
    for (int j = 0; j < 4; ++j) {
      float e0 = __builtin_amdgcn_exp2f(t0[j] - mr[j]);
      float e1 = __builtin_amdgcn_exp2f(t1[j] - mr[j]);
      ps[j] = e0 + e1;
      int row = qr*16 + l4*4 + j;
      int c0 = kh*32 + l15, c1 = c0 + 16;
      Plds[row*64 + (((c0 >> 3) ^ (row & 7)) << 3) + (c0 & 7)] = f2bf(e0);
      Plds[row*64 + (((c1 >> 3) ^ (row & 7)) << 3) + (c1 & 7)] = f2bf(e1);
    }
#pragma unroll
    for (int off = 8; off >= 1; off >>= 1)
#pragma unroll
      for (int j = 0; j < 4; ++j) ps[j] += __shfl_xor(ps[j], off);
    if (l15 == 0) {
#pragma unroll
      for (int j = 0; j < 4; ++j) psum_lds[(qr*16 + l4*4 + j)*2 + kh] = ps[j];
    }
    // O rescale by alpha (all waves, own d-slice)
#pragma unroll
    for (int mi = 0; mi < 4; ++mi) {
#pragma unroll
      for (int j = 0; j < 4; ++j) {
        float av = al_lds[mi*16 + l4*4 + j];
#pragma unroll
        for (int di = 0; di < 6; ++di) acc[mi][di][j] *= av;
      }
    }
    __syncthreads();                               // barrier3: P ready

    // ---- PV: O[64 q][96 d slice] += P * V ----
    const short* vbase = Vt + ((size_t)b*EMB + w*96) * SEQ + kc*64;
#pragma unroll
    for (int ks = 0; ks < 2; ++ks) {
      bf16x8 pa[4];
#pragma unroll
      for (int mi = 0; mi < 4; ++mi) {
        int row = mi*16 + l15;
        pa[mi] = *reinterpret_cast<const bf16x8*>(&Plds[row*64 + (((ks*4 + l4) ^ (row & 7)) << 3)]);
      }
#pragma unroll
      for (int di = 0; di < 6; ++di) {
        bf16x8 vb = *reinterpret_cast<const bf16x8*>(vbase + (size_t)(di*16 + l15) * SEQ + ks*32 + l4*8);
#pragma unroll
        for (int mi = 0; mi < 4; ++mi)
          acc[mi][di] = MFMA(pa[mi], vb, acc[mi][di]);
      }
    }

    asm volatile("s_waitcnt vmcnt(0)" ::: "memory"); // K stage complete (per-wave)
    __syncthreads();                                 // barrier4
  }

  // final l update + normalize + store
  if (tid < 64)
    l_lds[tid] = l_lds[tid] * al_lds[tid] + psum_lds[tid*2] + psum_lds[tid*2+1];
  __syncthreads();

  float* obase = out + ((size_t)(b*SEQ + qb*64)) * EMB + w*96;
#pragma unroll
  for (int mi = 0; mi < 4; ++mi) {
#pragma unroll
    for (int j = 0; j < 4; ++j) {
      float inv = 1.0f / l_lds[mi*16 + l4*4 + j];
#pragma unroll
      for (int di = 0; di < 6; ++di)
        obase[(size_t)(mi*16 + l4*4 + j) * EMB + di*16 + l15] = acc[mi][di][j] * inv;
    }
  }
}

// ---------------------------------------------------------------------------
extern "C" void kernel_launch(void* const* d_in, const int* in_sizes, int n_in,
                              void* d_out, int out_size, void* d_ws, size_t ws_size,
                              hipStream_t stream)
{
  (void)in_sizes; (void)n_in; (void)out_size; (void)ws_size;
  const float* x  = (const float*)d_in[0];
  const float* Wv = (const float*)d_in[1];
  const float* Wk = (const float*)d_in[2];
  const float* Wq = (const float*)d_in[3];
  const int* mask = (const int*)d_in[4];
  float* out = (float*)d_out;

  // workspace: Q | K | Vt, each 16384*768 bf16 (75.5 MB total)
  short* Qb = (short*)d_ws;
  short* Kb = Qb + (size_t)M_TOT * EMB;
  short* Vt = Kb + (size_t)M_TOT * EMB;

  qkv_gemm<<<dim3(2304), dim3(256), 0, stream>>>(x, Wq, Wk, Wv, Qb, Kb, Vt);

  size_t smem = (size_t)64*768*2 + 64*64*2 + 7*64*4;   // 108,288 B
  attn<<<dim3(256), dim3(512), smem, stream>>>(Qb, Kb, Vt, mask, out);
}

// Round 2
// 409.280 us; speedup vs baseline: 1.9161x; 1.9161x over previous
//
#include <hip/hip_runtime.h>
#include <stdint.h>

#define EMB 768
#define NBATCH 8
#define SEQ 2048
#define M_TOT (NBATCH*SEQ)   // 16384

using bf16x8 = __attribute__((ext_vector_type(8))) short;
using f32x4  = __attribute__((ext_vector_type(4))) float;

__device__ __forceinline__ short f2bf(float f) {
  __bf16 h = (__bf16)f;
  return __builtin_bit_cast(short, h);
}
__device__ __forceinline__ unsigned packbf(float a, float b) {
  return (unsigned)(unsigned short)f2bf(a) | ((unsigned)(unsigned short)f2bf(b) << 16);
}
__device__ __forceinline__ short f2h(float f) {
  _Float16 h = (_Float16)f;
  return __builtin_bit_cast(short, h);
}
__device__ __forceinline__ float h2f(short s) {
  return (float)__builtin_bit_cast(_Float16, s);
}
__device__ __forceinline__ f32x4 MFMA(bf16x8 a, bf16x8 b, f32x4 c) {
  return __builtin_amdgcn_mfma_f32_16x16x32_bf16(a, b, c, 0, 0, 0);
}
#define GLOAD_LDS16(g, l) __builtin_amdgcn_global_load_lds( \
    (const __attribute__((address_space(1))) unsigned int*)(g), \
    (__attribute__((address_space(3))) unsigned int*)(l), 16, 0, 0)

// ---------------------------------------------------------------------------
// QKV projection: C[m,f] = sum_e x[m,e]*W[f,e]. 128x128 tile, BK=64,
// reg-staged fp32->bf16, XOR-swizzled LDS, double-buffered. (unchanged, R1)
// V written transposed: Vt[b][d][s].
// ---------------------------------------------------------------------------
__global__ __launch_bounds__(256, 2) void qkv_gemm(
    const float* __restrict__ x, const float* __restrict__ Wq,
    const float* __restrict__ Wk, const float* __restrict__ Wv,
    short* __restrict__ Qb, short* __restrict__ Kb, short* __restrict__ Vt)
{
  __shared__ short As[2][128*64];
  __shared__ short Bs[2][128*64];

  const int bid = blockIdx.x;
  const int nb = (bid & 7) * 288 + (bid >> 3);     // XCD swizzle (2304 % 8 == 0)
  const int bm = nb / 18, bn = nb % 18;
  const int mbase = bm * 128;

  const int wi = bn / 6;                           // 0:Q 1:K 2:V
  const float* Wsrc = (wi == 0) ? Wq : (wi == 1) ? Wk : Wv;
  const float* xsrc = x + (size_t)mbase * EMB;
  const float* wsrc = Wsrc + (size_t)(bn % 6) * 128 * EMB;

  const int t = threadIdx.x;
  const int lane = t & 63, w = t >> 6;
  const int wm = w >> 1, wn = w & 1;
  const int l15 = lane & 15, l4 = lane >> 4;

  f32x4 acc[4][4] = {};
  float4 sa[4][2], sb[4][2];

  auto stage_load = [&](int kk) {
    const int k0 = kk * 64;
#pragma unroll
    for (int i = 0; i < 4; ++i) {
      int cid = i * 256 + t, row = cid >> 3, cc = cid & 7;
      const float4* pa = reinterpret_cast<const float4*>(xsrc + (size_t)row * EMB + k0 + cc * 8);
      sa[i][0] = pa[0]; sa[i][1] = pa[1];
      const float4* pb = reinterpret_cast<const float4*>(wsrc + (size_t)row * EMB + k0 + cc * 8);
      sb[i][0] = pb[0]; sb[i][1] = pb[1];
    }
  };
  auto stage_write = [&](int p) {
#pragma unroll
    for (int i = 0; i < 4; ++i) {
      int cid = i * 256 + t, row = cid >> 3, cc = cid & 7;
      int dst = row * 64 + ((cc ^ (row & 7)) << 3);
      int4 va, vb;
      va.x = (int)packbf(sa[i][0].x, sa[i][0].y); va.y = (int)packbf(sa[i][0].z, sa[i][0].w);
      va.z = (int)packbf(sa[i][1].x, sa[i][1].y); va.w = (int)packbf(sa[i][1].z, sa[i][1].w);
      *reinterpret_cast<int4*>(&As[p][dst]) = va;
      vb.x = (int)packbf(sb[i][0].x, sb[i][0].y); vb.y = (int)packbf(sb[i][0].z, sb[i][0].w);
      vb.z = (int)packbf(sb[i][1].x, sb[i][1].y); vb.w = (int)packbf(sb[i][1].z, sb[i][1].w);
      *reinterpret_cast<int4*>(&Bs[p][dst]) = vb;
    }
  };
  auto domfma = [&](int p) {
#pragma unroll
    for (int ks = 0; ks < 2; ++ks) {
      bf16x8 a[4], b[4];
#pragma unroll
      for (int i = 0; i < 4; ++i) {
        int ra = wm * 64 + i * 16 + l15;
        a[i] = *reinterpret_cast<const bf16x8*>(&As[p][ra * 64 + (((ks * 4 + l4) ^ (ra & 7)) << 3)]);
        int rb = wn * 64 + i * 16 + l15;
        b[i] = *reinterpret_cast<const bf16x8*>(&Bs[p][rb * 64 + (((ks * 4 + l4) ^ (rb & 7)) << 3)]);
      }
#pragma unroll
      for (int mi = 0; mi < 4; ++mi)
#pragma unroll
        for (int ni = 0; ni < 4; ++ni)
          acc[mi][ni] = MFMA(a[mi], b[ni], acc[mi][ni]);
    }
  };

  stage_load(0); stage_write(0);
  __syncthreads();
  for (int kk = 0; kk < 12; ++kk) {
    int p = kk & 1;
    if (kk < 11) stage_load(kk + 1);
    domfma(p);
    if (kk < 11) stage_write(p ^ 1);
    __syncthreads();
  }

#pragma unroll
  for (int mi = 0; mi < 4; ++mi) {
#pragma unroll
    for (int ni = 0; ni < 4; ++ni) {
      int f = bn * 128 + wn * 64 + ni * 16 + l15;
      int m0 = mbase + wm * 64 + mi * 16 + l4 * 4;
      f32x4 v = acc[mi][ni];
      if (f < 1536) {
        short* dst = (f < 768) ? (Qb + f) : (Kb + (f - 768));
#pragma unroll
        for (int j = 0; j < 4; ++j)
          dst[(size_t)(m0 + j) * EMB] = f2bf(v[j]);
      } else {
        int f2 = f - 1536, bb = m0 >> 11, s = m0 & 2047;
        short4 pk = make_short4(f2bf(v[0]), f2bf(v[1]), f2bf(v[2]), f2bf(v[3]));
        *reinterpret_cast<short4*>(&Vt[((size_t)bb * EMB + f2) * SEQ + s]) = pk;
      }
    }
  }
}

// ---------------------------------------------------------------------------
// energy: S'[b,q,k] = (Q[b,q,:]. K[b,k,:]) * log2e/sqrt(768), mask -> -3e4,
// stored fp16. m97-style: 128x128 tile, BK=64, gload_lds w16 staging with
// pre-swizzled global source (linear LDS dest), double-buffered.
// Grid 2048 = 8 batch x 16 qt x 16 kt; one batch per XCD; 4x4 supertile
// grouping for L2 (working set ~1.6MB < 4MB).
// ---------------------------------------------------------------------------
__global__ __launch_bounds__(256, 2) void energy(
    const short* __restrict__ Qb, const short* __restrict__ Kb,
    const int* __restrict__ mask, short* __restrict__ S)
{
  __shared__ short As[2][128*64];
  __shared__ short Bs[2][128*64];

  const int bid = blockIdx.x;
  const int nb = (bid & 7) * 256 + (bid >> 3);     // 2048 % 8 == 0, bijective
  const int b = nb >> 8;
  const int idx = nb & 255;
  const int sup = idx >> 4, sub = idx & 15;
  const int qt = (sup >> 2) * 4 + (sub >> 2);
  const int kt = (sup & 3) * 4 + (sub & 3);

  const short* qsrc = Qb + ((size_t)b*SEQ + qt*128) * EMB;
  const short* ksrc = Kb + ((size_t)b*SEQ + kt*128) * EMB;

  const int t = threadIdx.x, lane = t & 63, w = t >> 6;
  const int wm = w >> 1, wn = w & 1, l15 = lane & 15, l4 = lane >> 4;

  f32x4 acc[4][4] = {};

  auto stage = [&](int kk, int p) {
    const int k0 = kk * 64;
#pragma unroll
    for (int i = 0; i < 4; ++i) {
      int slot = i*256 + t;
      int row = slot >> 3, g = slot & 7;
      int gs = (g ^ (row & 7)) << 3;               // pre-swizzled source granule
      GLOAD_LDS16(qsrc + (size_t)row*EMB + k0 + gs,
                  (char*)&As[p][0] + (size_t)(i*256 + w*64)*16);
      GLOAD_LDS16(ksrc + (size_t)row*EMB + k0 + gs,
                  (char*)&Bs[p][0] + (size_t)(i*256 + w*64)*16);
    }
  };
  auto domfma = [&](int p) {
#pragma unroll
    for (int ks = 0; ks < 2; ++ks) {
      bf16x8 a[4], bb[4];
#pragma unroll
      for (int i = 0; i < 4; ++i) {
        int ra = wm*64 + i*16 + l15;
        a[i]  = *reinterpret_cast<const bf16x8*>(&As[p][ra*64 + (((ks*4 + l4) ^ (ra & 7)) << 3)]);
        int rb = wn*64 + i*16 + l15;
        bb[i] = *reinterpret_cast<const bf16x8*>(&Bs[p][rb*64 + (((ks*4 + l4) ^ (rb & 7)) << 3)]);
      }
#pragma unroll
      for (int mi = 0; mi < 4; ++mi)
#pragma unroll
        for (int ni = 0; ni < 4; ++ni)
          acc[mi][ni] = MFMA(a[mi], bb[ni], acc[mi][ni]);
    }
  };

  stage(0, 0);
  asm volatile("s_waitcnt vmcnt(0)" ::: "memory");
  __syncthreads();
  for (int kk = 0; kk < 12; ++kk) {
    int p = kk & 1;
    if (kk < 11) stage(kk + 1, p ^ 1);
    domfma(p);
    asm volatile("s_waitcnt vmcnt(0)" ::: "memory");
    __syncthreads();
  }

  const float SCL = 1.4426950408889634f / 27.712812921102035f;  // log2e/sqrt(768)
  short* srow = S + (size_t)b * SEQ * SEQ;
  const int* mrow = mask + (size_t)b * SEQ * SEQ;
#pragma unroll
  for (int mi = 0; mi < 4; ++mi) {
#pragma unroll
    for (int j = 0; j < 4; ++j) {
      int q = qt*128 + wm*64 + mi*16 + l4*4 + j;
#pragma unroll
      for (int ni = 0; ni < 4; ++ni) {
        int k = kt*128 + wn*64 + ni*16 + l15;
        float v = acc[mi][ni][j] * SCL;
        int mv = mrow[(size_t)q*SEQ + k];
        srow[(size_t)q*SEQ + k] = f2h(mv != 0 ? v : -30000.0f);
      }
    }
  }
}

// ---------------------------------------------------------------------------
// softmax_rows: one wave per row. Read 2048 fp16 scores (exp2 units),
// row max + exp2 + sum, overwrite row IN PLACE with bf16 P = exp2(s - m),
// store invl = 1/sum. 16384 rows, 4 waves/block -> 4096 blocks.
// ---------------------------------------------------------------------------
__global__ __launch_bounds__(256, 8) void softmax_rows(
    short* __restrict__ S, float* __restrict__ invl)
{
  const int w = threadIdx.x >> 6, lane = threadIdx.x & 63;
  const int r = blockIdx.x * 4 + w;
  short* row = S + (size_t)r * SEQ;

  bf16x8 v[4];
  float f[32];
#pragma unroll
  for (int c = 0; c < 4; ++c) {
    v[c] = *reinterpret_cast<const bf16x8*>(&row[c*512 + lane*8]);
#pragma unroll
    for (int j = 0; j < 8; ++j) f[c*8 + j] = h2f(v[c][j]);
  }
  float m = -3.0e38f;
#pragma unroll
  for (int i = 0; i < 32; ++i) m = fmaxf(m, f[i]);
#pragma unroll
  for (int off = 32; off >= 1; off >>= 1) m = fmaxf(m, __shfl_xor(m, off));
  float sum = 0.f;
#pragma unroll
  for (int i = 0; i < 32; ++i) {
    f[i] = __builtin_amdgcn_exp2f(f[i] - m);
    sum += f[i];
  }
#pragma unroll
  for (int off = 32; off >= 1; off >>= 1) sum += __shfl_xor(sum, off);

#pragma unroll
  for (int c = 0; c < 4; ++c) {
    bf16x8 o;
#pragma unroll
    for (int j = 0; j < 8; ++j) o[j] = f2bf(f[c*8 + j]);
    *reinterpret_cast<bf16x8*>(&row[c*512 + lane*8]) = o;
  }
  if (lane == 0) invl[r] = 1.0f / sum;
}

// ---------------------------------------------------------------------------
// pv: out[b,q,d] = invl[b,q] * sum_k P[b,q,k] * Vt[b,d,k]. Same GEMM
// structure, K-loop 32 (2048/64). Grid 768 = 8 x 16 qt x 6 dt.
// ---------------------------------------------------------------------------
__global__ __launch_bounds__(256, 2) void pv(
    const short* __restrict__ P, const short* __restrict__ Vt,
    const float* __restrict__ invl, float* __restrict__ out)
{
  __shared__ short As[2][128*64];
  __shared__ short Bs[2][128*64];

  const int bid = blockIdx.x;
  const int nb = (bid & 7) * 96 + (bid >> 3);      // 768 % 8 == 0, bijective
  const int b = nb / 96;
  const int idx = nb % 96;
  const int qt = idx / 6, dt = idx % 6;

  const short* psrc = P  + ((size_t)b*SEQ + qt*128) * SEQ;
  const short* vsrc = Vt + ((size_t)b*EMB + dt*128) * SEQ;

  const int t = threadIdx.x, lane = t & 63, w = t >> 6;
  const int wm = w >> 1, wn = w & 1, l15 = lane & 15, l4 = lane >> 4;

  f32x4 acc[4][4] = {};

  auto stage = [&](int kk, int p) {
    const int k0 = kk * 64;
#pragma unroll
    for (int i = 0; i < 4; ++i) {
      int slot = i*256 + t;
      int row = slot >> 3, g = slot & 7;
      int gs = (g ^ (row & 7)) << 3;
      GLOAD_LDS16(psrc + (size_t)row*SEQ + k0 + gs,
                  (char*)&As[p][0] + (size_t)(i*256 + w*64)*16);
      GLOAD_LDS16(vsrc + (size_t)row*SEQ + k0 + gs,
                  (char*)&Bs[p][0] + (size_t)(i*256 + w*64)*16);
    }
  };
  auto domfma = [&](int p) {
#pragma unroll
    for (int ks = 0; ks < 2; ++ks) {
      bf16x8 a[4], bb[4];
#pragma unroll
      for (int i = 0; i < 4; ++i) {
        int ra = wm*64 + i*16 + l15;
        a[i]  = *reinterpret_cast<const bf16x8*>(&As[p][ra*64 + (((ks*4 + l4) ^ (ra & 7)) << 3)]);
        int rb = wn*64 + i*16 + l15;
        bb[i] = *reinterpret_cast<const bf16x8*>(&Bs[p][rb*64 + (((ks*4 + l4) ^ (rb & 7)) << 3)]);
      }
#pragma unroll
      for (int mi = 0; mi < 4; ++mi)
#pragma unroll
        for (int ni = 0; ni < 4; ++ni)
          acc[mi][ni] = MFMA(a[mi], bb[ni], acc[mi][ni]);
    }
  };

  stage(0, 0);
  asm volatile("s_waitcnt vmcnt(0)" ::: "memory");
  __syncthreads();
  for (int kk = 0; kk < 32; ++kk) {
    int p = kk & 1;
    if (kk < 31) stage(kk + 1, p ^ 1);
    domfma(p);
    asm volatile("s_waitcnt vmcnt(0)" ::: "memory");
    __syncthreads();
  }

#pragma unroll
  for (int mi = 0; mi < 4; ++mi) {
#pragma unroll
    for (int j = 0; j < 4; ++j) {
      int q = qt*128 + wm*64 + mi*16 + l4*4 + j;
      float il = invl[b*SEQ + q];
      float* orow = out + ((size_t)b*SEQ + q) * EMB;
#pragma unroll
      for (int ni = 0; ni < 4; ++ni) {
        int d = dt*128 + wn*64 + ni*16 + l15;
        orow[d] = acc[mi][ni][j] * il;
      }
    }
  }
}

// ---------------------------------------------------------------------------
extern "C" void kernel_launch(void* const* d_in, const int* in_sizes, int n_in,
                              void* d_out, int out_size, void* d_ws, size_t ws_size,
                              hipStream_t stream)
{
  (void)in_sizes; (void)n_in; (void)out_size; (void)ws_size;
  const float* x  = (const float*)d_in[0];
  const float* Wv = (const float*)d_in[1];
  const float* Wk = (const float*)d_in[2];
  const float* Wq = (const float*)d_in[3];
  const int* mask = (const int*)d_in[4];
  float* out = (float*)d_out;

  // ws: Q | K | Vt (bf16, 24MB each) | S/P (fp16->bf16 in place, 67MB) | invl
  short* Qb = (short*)d_ws;
  short* Kb = Qb + (size_t)M_TOT * EMB;
  short* Vt = Kb + (size_t)M_TOT * EMB;
  short* S  = Vt + (size_t)M_TOT * EMB;
  float* invl = (float*)(S + (size_t)NBATCH * SEQ * SEQ);

  qkv_gemm<<<dim3(2304), dim3(256), 0, stream>>>(x, Wq, Wk, Wv, Qb, Kb, Vt);
  energy<<<dim3(2048), dim3(256), 0, stream>>>(Qb, Kb, mask, S);
  softmax_rows<<<dim3(4096), dim3(256), 0, stream>>>(S, invl);
  pv<<<dim3(768), dim3(256), 0, stream>>>(S, Vt, invl, out);
}

// Round 3
// 245.768 us; speedup vs baseline: 3.1909x; 1.6653x over previous
//
#include <hip/hip_runtime.h>
#include <stdint.h>

#define EMB 768
#define NBATCH 8
#define SEQ 2048
#define M_TOT (NBATCH*SEQ)   // 16384

using bf16x8 = __attribute__((ext_vector_type(8))) short;
using f32x4  = __attribute__((ext_vector_type(4))) float;

__device__ __forceinline__ short f2bf(float f) {
  __bf16 h = (__bf16)f;
  return __builtin_bit_cast(short, h);
}
__device__ __forceinline__ short f2h(float f) {
  _Float16 h = (_Float16)f;
  return __builtin_bit_cast(short, h);
}
__device__ __forceinline__ float h2f(short s) {
  return (float)__builtin_bit_cast(_Float16, s);
}
__device__ __forceinline__ f32x4 MFMA(bf16x8 a, bf16x8 b, f32x4 c) {
  return __builtin_amdgcn_mfma_f32_16x16x32_bf16(a, b, c, 0, 0, 0);
}
#define GLOAD_LDS16(g, l) __builtin_amdgcn_global_load_lds( \
    (const __attribute__((address_space(1))) unsigned int*)(g), \
    (__attribute__((address_space(3))) unsigned int*)(l), 16, 0, 0)

// ---------------------------------------------------------------------------
// cvt_all: x (fp32->bf16) -> xb; Wq|Wk|Wv (fp32->bf16) -> Wb[2304][768]
// (rows 0..767 = Wq, 768..1535 = Wk, 1536..2303 = Wv). Streaming, 8 elems/it.
// ---------------------------------------------------------------------------
__global__ __launch_bounds__(256) void cvt_all(
    const float* __restrict__ x, const float* __restrict__ Wq,
    const float* __restrict__ Wk, const float* __restrict__ Wv,
    short* __restrict__ xb, short* __restrict__ Wb)
{
  const size_t NXU = (size_t)M_TOT * EMB / 8;      // 1,572,864
  const size_t NWU = (size_t)EMB * EMB / 8;        // 73,728
  const size_t total = NXU + 3 * NWU;
  for (size_t u = (size_t)blockIdx.x * 256 + threadIdx.x; u < total;
       u += (size_t)gridDim.x * 256) {
    const float* src; short* dst; size_t off;
    if (u < NXU)            { src = x;  dst = xb;                          off = u; }
    else if (u < NXU+NWU)   { src = Wq; dst = Wb;                          off = u - NXU; }
    else if (u < NXU+2*NWU) { src = Wk; dst = Wb + (size_t)EMB*EMB;        off = u - NXU - NWU; }
    else                    { src = Wv; dst = Wb + (size_t)2*EMB*EMB;      off = u - NXU - 2*NWU; }
    float4 a = reinterpret_cast<const float4*>(src)[off*2];
    float4 c = reinterpret_cast<const float4*>(src)[off*2+1];
    bf16x8 o;
    o[0]=f2bf(a.x); o[1]=f2bf(a.y); o[2]=f2bf(a.z); o[3]=f2bf(a.w);
    o[4]=f2bf(c.x); o[5]=f2bf(c.y); o[6]=f2bf(c.z); o[7]=f2bf(c.w);
    reinterpret_cast<bf16x8*>(dst)[off] = o;
  }
}

// ---------------------------------------------------------------------------
// Shared GEMM machinery: m97 single-buffer 2-barrier loop, 128x128 tile,
// BK=64, gload_lds w16 with pre-swizzled source (linear LDS dest),
// XOR-swizzled ds_read_b128. 32KB LDS -> 4 blocks/CU at <=128 VGPR.
// ---------------------------------------------------------------------------
#define GEMM_STAGE(As, Bs, asrc, bsrc, lda, ldb)                             \
  {                                                                          \
    _Pragma("unroll")                                                        \
    for (int i = 0; i < 4; ++i) {                                            \
      int slot = i*256 + t;                                                  \
      int row = slot >> 3, g = slot & 7;                                     \
      int gs = (g ^ (row & 7)) << 3;                                         \
      GLOAD_LDS16((asrc) + (size_t)row*(lda) + gs,                           \
                  (char*)&As[0] + (size_t)(i*256 + w*64)*16);                \
      GLOAD_LDS16((bsrc) + (size_t)row*(ldb) + gs,                           \
                  (char*)&Bs[0] + (size_t)(i*256 + w*64)*16);                \
    }                                                                        \
  }

#define GEMM_MFMA(As, Bs)                                                    \
  {                                                                          \
    _Pragma("unroll")                                                        \
    for (int ks = 0; ks < 2; ++ks) {                                         \
      bf16x8 a[4], bb[4];                                                    \
      _Pragma("unroll")                                                      \
      for (int i = 0; i < 4; ++i) {                                          \
        int ra = wm*64 + i*16 + l15;                                         \
        a[i]  = *reinterpret_cast<const bf16x8*>(                            \
                  &As[ra*64 + (((ks*4 + l4) ^ (ra & 7)) << 3)]);             \
        int rb = wn*64 + i*16 + l15;                                         \
        bb[i] = *reinterpret_cast<const bf16x8*>(                            \
                  &Bs[rb*64 + (((ks*4 + l4) ^ (rb & 7)) << 3)]);             \
      }                                                                      \
      _Pragma("unroll")                                                      \
      for (int mi = 0; mi < 4; ++mi)                                         \
        _Pragma("unroll")                                                    \
        for (int ni = 0; ni < 4; ++ni)                                       \
          acc[mi][ni] = MFMA(a[mi], bb[ni], acc[mi][ni]);                    \
    }                                                                        \
  }

// ---------------------------------------------------------------------------
// qkv: C[m,f] = sum_e xb[m,e]*Wb[f,e] (bf16 GEMM). Q/K row-major, V
// transposed (Vt[b][d][s]). Grid 2304 = 128 bm x 18 bn, 4x3 supertiles.
// ---------------------------------------------------------------------------
__global__ __launch_bounds__(256, 4) void qkv_gemm(
    const short* __restrict__ xb, const short* __restrict__ Wb,
    short* __restrict__ Qb, short* __restrict__ Kb, short* __restrict__ Vt)
{
  __shared__ short As[128*64];
  __shared__ short Bs[128*64];

  const int bid = blockIdx.x;
  const int nb = (bid & 7) * 288 + (bid >> 3);     // XCD swizzle, 2304%8==0
  const int g = nb / 12, r = nb % 12;              // 4bm x 3bn supertiles
  const int bm = (g / 6) * 4 + r / 3;
  const int bn = (g % 6) * 3 + r % 3;
  const int mbase = bm * 128;

  const short* asrc = xb + (size_t)mbase * EMB;
  const short* bsrc = Wb + (size_t)bn * 128 * EMB;

  const int t = threadIdx.x, lane = t & 63, w = t >> 6;
  const int wm = w >> 1, wn = w & 1, l15 = lane & 15, l4 = lane >> 4;

  f32x4 acc[4][4] = {};

  GEMM_STAGE(As, Bs, asrc, bsrc, EMB, EMB);
  for (int kk = 0; kk < 12; ++kk) {
    asm volatile("s_waitcnt vmcnt(0)" ::: "memory");
    __syncthreads();
    GEMM_MFMA(As, Bs);
    if (kk < 11) {
      __syncthreads();
      GEMM_STAGE(As, Bs, asrc + (kk+1)*64, bsrc + (kk+1)*64, EMB, EMB);
    }
  }

#pragma unroll
  for (int mi = 0; mi < 4; ++mi) {
#pragma unroll
    for (int ni = 0; ni < 4; ++ni) {
      int f = bn * 128 + wn * 64 + ni * 16 + l15;
      int m0 = mbase + wm * 64 + mi * 16 + l4 * 4;
      f32x4 v = acc[mi][ni];
      if (f < 1536) {
        short* dst = (f < 768) ? (Qb + f) : (Kb + (f - 768));
#pragma unroll
        for (int j = 0; j < 4; ++j)
          dst[(size_t)(m0 + j) * EMB] = f2bf(v[j]);
      } else {
        int f2 = f - 1536, bb2 = m0 >> 11, s = m0 & 2047;
        short4 pk = make_short4(f2bf(v[0]), f2bf(v[1]), f2bf(v[2]), f2bf(v[3]));
        *reinterpret_cast<short4*>(&Vt[((size_t)bb2 * EMB + f2) * SEQ + s]) = pk;
      }
    }
  }
}

// ---------------------------------------------------------------------------
// energy: S[b,q,k] = (Q[b,q,:].K[b,k,:]) * log2e/sqrt(768), fp16. No mask
// here (applied in softmax). Grid 2048 = 8 b x (4x4 supertiles of 16qt x 16kt).
// ---------------------------------------------------------------------------
__global__ __launch_bounds__(256, 4) void energy(
    const short* __restrict__ Qb, const short* __restrict__ Kb,
    short* __restrict__ S)
{
  __shared__ short As[128*64];
  __shared__ short Bs[128*64];

  const int bid = blockIdx.x;
  const int nb = (bid & 7) * 256 + (bid >> 3);
  const int b = nb >> 8;
  const int idx = nb & 255;
  const int sup = idx >> 4, sub = idx & 15;
  const int qt = (sup >> 2) * 4 + (sub >> 2);
  const int kt = (sup & 3) * 4 + (sub & 3);

  const short* asrc = Qb + ((size_t)b*SEQ + qt*128) * EMB;
  const short* bsrc = Kb + ((size_t)b*SEQ + kt*128) * EMB;

  const int t = threadIdx.x, lane = t & 63, w = t >> 6;
  const int wm = w >> 1, wn = w & 1, l15 = lane & 15, l4 = lane >> 4;

  f32x4 acc[4][4] = {};

  GEMM_STAGE(As, Bs, asrc, bsrc, EMB, EMB);
  for (int kk = 0; kk < 12; ++kk) {
    asm volatile("s_waitcnt vmcnt(0)" ::: "memory");
    __syncthreads();
    GEMM_MFMA(As, Bs);
    if (kk < 11) {
      __syncthreads();
      GEMM_STAGE(As, Bs, asrc + (kk+1)*64, bsrc + (kk+1)*64, EMB, EMB);
    }
  }

  const float SCL = 1.4426950408889634f / 27.712812921102035f;  // log2e/sqrt(768)
  short* srow = S + (size_t)b * SEQ * SEQ;
#pragma unroll
  for (int mi = 0; mi < 4; ++mi) {
#pragma unroll
    for (int j = 0; j < 4; ++j) {
      int q = qt*128 + wm*64 + mi*16 + l4*4 + j;
#pragma unroll
      for (int ni = 0; ni < 4; ++ni) {
        int k = kt*128 + wn*64 + ni*16 + l15;
        srow[(size_t)q*SEQ + k] = f2h(acc[mi][ni][j] * SCL);
      }
    }
  }
}

// ---------------------------------------------------------------------------
// softmax_rows: one wave per row. Read 2048 fp16 scores + 2048 int32 mask
// (streaming int4), apply mask (-30000), row max + exp2 + sum, overwrite row
// with bf16 P, store invl = 1/sum. 16384 rows, 4 waves/block.
// ---------------------------------------------------------------------------
__global__ __launch_bounds__(256, 8) void softmax_rows(
    short* __restrict__ S, const int* __restrict__ mask,
    float* __restrict__ invl)
{
  const int w = threadIdx.x >> 6, lane = threadIdx.x & 63;
  const int r = blockIdx.x * 4 + w;
  short* row = S + (size_t)r * SEQ;
  const int4* mrow = reinterpret_cast<const int4*>(mask + (size_t)r * SEQ);

  float f[32];
#pragma unroll
  for (int c = 0; c < 4; ++c) {
    bf16x8 v = *reinterpret_cast<const bf16x8*>(&row[c*512 + lane*8]);
    int4 m0 = mrow[(c*512 + lane*8) >> 2];
    int4 m1 = mrow[((c*512 + lane*8) >> 2) + 1];
    f[c*8+0] = m0.x ? h2f(v[0]) : -30000.0f;
    f[c*8+1] = m0.y ? h2f(v[1]) : -30000.0f;
    f[c*8+2] = m0.z ? h2f(v[2]) : -30000.0f;
    f[c*8+3] = m0.w ? h2f(v[3]) : -30000.0f;
    f[c*8+4] = m1.x ? h2f(v[4]) : -30000.0f;
    f[c*8+5] = m1.y ? h2f(v[5]) : -30000.0f;
    f[c*8+6] = m1.z ? h2f(v[6]) : -30000.0f;
    f[c*8+7] = m1.w ? h2f(v[7]) : -30000.0f;
  }
  float m = -3.0e38f;
#pragma unroll
  for (int i = 0; i < 32; ++i) m = fmaxf(m, f[i]);
#pragma unroll
  for (int off = 32; off >= 1; off >>= 1) m = fmaxf(m, __shfl_xor(m, off));
  float sum = 0.f;
#pragma unroll
  for (int i = 0; i < 32; ++i) {
    f[i] = __builtin_amdgcn_exp2f(f[i] - m);
    sum += f[i];
  }
#pragma unroll
  for (int off = 32; off >= 1; off >>= 1) sum += __shfl_xor(sum, off);

#pragma unroll
  for (int c = 0; c < 4; ++c) {
    bf16x8 o;
#pragma unroll
    for (int j = 0; j < 8; ++j) o[j] = f2bf(f[c*8 + j]);
    *reinterpret_cast<bf16x8*>(&row[c*512 + lane*8]) = o;
  }
  if (lane == 0) invl[r] = 1.0f / sum;
}

// ---------------------------------------------------------------------------
// pv: out[b,q,d] = invl[b,q] * sum_k P[b,q,k] * Vt[b,d,k].
// Grid 768 = 8 b x 16 qt x 6 dt; K-loop 32.
// ---------------------------------------------------------------------------
__global__ __launch_bounds__(256, 4) void pv(
    const short* __restrict__ P, const short* __restrict__ Vt,
    const float* __restrict__ invl, float* __restrict__ out)
{
  __shared__ short As[128*64];
  __shared__ short Bs[128*64];

  const int bid = blockIdx.x;
  const int nb = (bid & 7) * 96 + (bid >> 3);
  const int b = nb / 96;
  const int idx = nb % 96;
  const int qt = idx / 6, dt = idx % 6;

  const short* asrc = P  + ((size_t)b*SEQ + qt*128) * SEQ;
  const short* bsrc = Vt + ((size_t)b*EMB + dt*128) * SEQ;

  const int t = threadIdx.x, lane = t & 63, w = t >> 6;
  const int wm = w >> 1, wn = w & 1, l15 = lane & 15, l4 = lane >> 4;

  f32x4 acc[4][4] = {};

  GEMM_STAGE(As, Bs, asrc, bsrc, SEQ, SEQ);
  for (int kk = 0; kk < 32; ++kk) {
    asm volatile("s_waitcnt vmcnt(0)" ::: "memory");
    __syncthreads();
    GEMM_MFMA(As, Bs);
    if (kk < 31) {
      __syncthreads();
      GEMM_STAGE(As, Bs, asrc + (kk+1)*64, bsrc + (kk+1)*64, SEQ, SEQ);
    }
  }

#pragma unroll
  for (int mi = 0; mi < 4; ++mi) {
#pragma unroll
    for (int j = 0; j < 4; ++j) {
      int q = qt*128 + wm*64 + mi*16 + l4*4 + j;
      float il = invl[b*SEQ + q];
      float* orow = out + ((size_t)b*SEQ + q) * EMB;
#pragma unroll
      for (int ni = 0; ni < 4; ++ni) {
        int d = dt*128 + wn*64 + ni*16 + l15;
        orow[d] = acc[mi][ni][j] * il;
      }
    }
  }
}

// ---------------------------------------------------------------------------
extern "C" void kernel_launch(void* const* d_in, const int* in_sizes, int n_in,
                              void* d_out, int out_size, void* d_ws, size_t ws_size,
                              hipStream_t stream)
{
  (void)in_sizes; (void)n_in; (void)out_size; (void)ws_size;
  const float* x  = (const float*)d_in[0];
  const float* Wv = (const float*)d_in[1];
  const float* Wk = (const float*)d_in[2];
  const float* Wq = (const float*)d_in[3];
  const int* mask = (const int*)d_in[4];
  float* out = (float*)d_out;

  // ws: Qb | Kb | Vt (bf16, 24MiB each) | S (fp16->bf16 in place, 64MiB) | invl
  // xb and Wb alias the S region (dead before energy writes S).
  short* Qb = (short*)d_ws;
  short* Kb = Qb + (size_t)M_TOT * EMB;
  short* Vt = Kb + (size_t)M_TOT * EMB;
  short* S  = Vt + (size_t)M_TOT * EMB;
  float* invl = (float*)(S + (size_t)NBATCH * SEQ * SEQ);
  short* xb = S;                                   // 24 MiB
  short* Wb = S + (size_t)M_TOT * EMB;             // 3.4 MiB

  cvt_all<<<dim3(2048), dim3(256), 0, stream>>>(x, Wq, Wk, Wv, xb, Wb);
  qkv_gemm<<<dim3(2304), dim3(256), 0, stream>>>(xb, Wb, Qb, Kb, Vt);
  energy<<<dim3(2048), dim3(256), 0, stream>>>(Qb, Kb, S);
  softmax_rows<<<dim3(4096), dim3(256), 0, stream>>>(S, mask, invl);
  pv<<<dim3(768), dim3(256), 0, stream>>>(S, Vt, invl, out);
}